// Round 18
// baseline (250.206 us; speedup 1.0000x reference)
//
#include <hip/hip_runtime.h>
#include <cmath>

// ---------------------------------------------------------------------------
// Workspace layout (float offsets). Total 19,801,344 floats ~= 79.2 MB.
//  XB  = 0          xb bf16 [4][4096 pix][256 c]   (later: inb conv input)
//  QB  = 2,097,152  Q tokens bf16 [n][d]
//  KB  = 4,194,304  K tokens bf16 [n][d]
//  VB  = 6,291,456  V^T tokens bf16, 4 scales x [4][D][N]
//  SS  = 8,388,608  S2 scores bf16 [4][1024][1024] (ushort)
//  PP  = 12,582,912 P2 bf16 [4][1024][1024]
//  YT  = 14,680,064 conv out z bf16 [4][256][64][64]
//  WQK = 18,874,368 Wqkv bf16 [768][256]
//  BIA = 18,972,672 stacked qkv bias fp32 [768]
//  WCV = 18,973,440 conv weights bf16 [9][256][256]
//  STT = 19,268,352 bn stats [512]
//  SP0 = 19,268,864 s0 score partials [32][64][64] fp32
//  S1  = 19,399,936 s1 scores bf16 [4][256][256] (ushort)
//  P0  = 19,662,080 s0 P bf16 (16384 ush)
//  P1  = 19,670,272 s1 P bf16 (262144 ush)
// ---------------------------------------------------------------------------

#define OFF_XB  0LL
#define OFF_QB  2097152LL
#define OFF_SS  8388608LL
#define OFF_PP  12582912LL
#define OFF_YT  14680064LL
#define OFF_WQK 18874368LL
#define OFF_BIA 18972672LL
#define OFF_WCV 18973440LL
#define OFF_STT 19268352LL
#define OFF_SP0 19268864LL
#define OFF_S1  19399936LL
#define OFF_P0  19662080LL
#define OFF_P1  19670272LL

#define FC 0.18033688f   // 0.125 * log2(e)
#define CSHIFT 6.0f      // static softmax shift (exp2 domain)

typedef __attribute__((ext_vector_type(8))) short short8;
typedef __attribute__((ext_vector_type(4))) float f32x4;

__device__ inline unsigned short f2bf(float f) {
  unsigned u = __float_as_uint(f);
  u += 0x7fff + ((u >> 16) & 1);
  return (unsigned short)(u >> 16);
}

__device__ inline float bf2f(unsigned short h) {
  return __uint_as_float((unsigned)h << 16);
}

__device__ inline unsigned cvt_pk_bf16(float a, float b) {
  unsigned r;
  asm("v_cvt_pk_bf16_f32 %0, %1, %2" : "=v"(r) : "v"(a), "v"(b));
  return r;   // lo16 = bf16(a), hi16 = bf16(b)
}

// ====================== merged prep: xpose + wcvt + wconv ==================
__global__ __launch_bounds__(256) void prep_k(
    const float* __restrict__ x, unsigned short* __restrict__ xb,
    const float* __restrict__ wq, const float* __restrict__ wk,
    const float* __restrict__ wv, const float* __restrict__ bq,
    const float* __restrict__ bk, const float* __restrict__ bv,
    unsigned short* __restrict__ Wqkv, float* __restrict__ biasQKV,
    const float* __restrict__ wcv, unsigned short* __restrict__ Wcb)
{
  const int bid = blockIdx.x, t = threadIdx.x;
  if (bid < 256) {
    __shared__ unsigned short rowb[256][66];
    const int b = bid >> 6, y = bid & 63;
    for (int i = t; i < 16384; i += 256) {
      int c = i >> 6, xx = i & 63;
      rowb[c][xx] = f2bf(x[((long long)(b*256 + c) << 12) + (y << 6) + xx]);
    }
    __syncthreads();
    unsigned int* outw = (unsigned int*)(xb + ((long long)bid << 14));
    for (int i = t; i < 8192; i += 256) {
      int xx = i >> 7, c2 = (i & 127) * 2;
      outw[xx*128 + (c2 >> 1)] = (unsigned)rowb[c2][xx]
                               | ((unsigned)rowb[c2+1][xx] << 16);
    }
  } else if (bid < 1024) {
    const int row = bid - 256;
    const int which = row >> 8, oc = row & 255;
    const float* src = which == 0 ? wq : which == 1 ? wk : wv;
    Wqkv[row*256 + t] = f2bf(src[oc*256 + t]);
    if (row < 3) {
      const float* bs = row == 0 ? bq : row == 1 ? bk : bv;
      biasQKV[row*256 + t] = bs[t];
    }
  } else {
    int i = (bid - 1024)*256 + t;    // < 589824
    int tap = i >> 16, oc = (i >> 8) & 255, ic = i & 255;
    Wcb[i] = f2bf(wcv[((long long)(oc*256 + ic))*9 + tap]);
  }
}

// ====================== bf16 MFMA NT GEMM body (no LDS) ====================
// EPI 0: fp32 C row-major.   EPI 1: QKV token scatter (bf16 + bias).
// EPI 2: PV -> bf16 NHWC scatter.  EPI 3: bf16 C row-major (alpha applied).
template<int EPI, int SH = 0>
__device__ void gemm_nt_body(
    const unsigned short* __restrict__ A, const unsigned short* __restrict__ B,
    void* __restrict__ Cv, const float* __restrict__ bias,
    int M, int N, int K, int lda, int ldb, int ldc,
    long long sA, long long sB, long long sC, float alpha,
    int bx, int by, int bz)
{
  const int t = threadIdx.x, l = t & 63;
  const int lr = l & 15, lg = l >> 4;
  const int w = t >> 6, wm = w >> 1, wn = w & 1;
  const int m0 = by*128 + wm*64, n0 = bx*128 + wn*64;
  if (m0 >= M || n0 >= N) return;
  const unsigned short* Ab = A + (long long)bz*sA + (long long)(m0 + lr)*lda + lg*8;
  const unsigned short* Bb = B + (long long)bz*sB + (long long)(n0 + lr)*ldb + lg*8;

  f32x4 acc[4][4] = {};
#pragma unroll 2
  for (int kk = 0; kk < K; kk += 32) {
    short8 af[4], bf[4];
#pragma unroll
    for (int i = 0; i < 4; i++)
      af[i] = *(const short8*)(Ab + (long long)i*16*lda + kk);
#pragma unroll
    for (int i = 0; i < 4; i++)
      bf[i] = *(const short8*)(Bb + (long long)i*16*ldb + kk);
#pragma unroll
    for (int mf = 0; mf < 4; mf++)
#pragma unroll
      for (int nf = 0; nf < 4; nf++)
        acc[mf][nf] = __builtin_amdgcn_mfma_f32_16x16x32_bf16(
            af[mf], bf[nf], acc[mf][nf], 0, 0, 0);
  }

  if (EPI == 0) {
    float* C = (float*)Cv + (long long)bz*sC;
#pragma unroll
    for (int mf = 0; mf < 4; mf++)
#pragma unroll
      for (int r = 0; r < 4; r++) {
        const int row = m0 + mf*16 + lg*4 + r;
#pragma unroll
        for (int nf = 0; nf < 4; nf++)
          C[(long long)row*ldc + n0 + nf*16 + lr] = acc[mf][nf][r] * alpha;
      }
  } else if (EPI == 1) {
    unsigned short* Qbase = (unsigned short*)Cv;
#pragma unroll
    for (int mf = 0; mf < 4; mf++)
#pragma unroll
      for (int r = 0; r < 4; r++) {
        const int gi = m0 + mf*16 + lg*4 + r;          // 0..767
        const int which = gi >> 8, ch = gi & 255;
        const int scale = ch >> 6, c = ch & 63;
        const int sh = 3 - scale, msk = (1 << sh) - 1;
        const bool tr = (which == 2);                  // only V transposed
        const float bb = bias[gi];
        unsigned short* dst = Qbase + (long long)which*4194304
                            + (long long)scale*1048576 + (long long)bz*262144;
#pragma unroll
        for (int nf = 0; nf < 4; nf++) {
          const int gj = n0 + nf*16 + lr;              // pixel
          const int y = gj >> 6, xx = gj & 63;
          const int n = (y >> sh)*(64 >> sh) + (xx >> sh);
          const int d = (c << (2*sh)) + ((y & msk) << sh) + (xx & msk);
          const long long idx = tr
              ? (long long)d*(4096 >> (2*sh)) + n      // [d][n]
              : (long long)n*(64 << (2*sh)) + d;       // [n][d]
          dst[idx] = f2bf(acc[mf][nf][r] + bb);
        }
      }
  } else if (EPI == 2) {
    // EPI 2: token/dim -> bf16 NHWC (channels (3-SH)*64 .. +63)
    unsigned short* inb = (unsigned short*)Cv;
    constexpr int msk = (1 << SH) - 1;
    constexpr int scale = 3 - SH;
#pragma unroll
    for (int mf = 0; mf < 4; mf++)
#pragma unroll
      for (int r = 0; r < 4; r++) {
        const int gi = m0 + mf*16 + lg*4 + r;          // token n
        const int ty = gi >> (6 - SH), tx = gi & ((64 >> SH) - 1);
#pragma unroll
        for (int nf = 0; nf < 4; nf++) {
          const int gj = n0 + nf*16 + lr;              // dim d
          const int c = gj >> (2*SH);
          const int y = (ty << SH) | ((gj >> SH) & msk);
          const int x = (tx << SH) | (gj & msk);
          inb[((((long long)bz << 12) + (y << 6) + x) << 8) + scale*64 + c]
              = f2bf(acc[mf][nf][r]);
        }
      }
  } else {
    // EPI 3: bf16 C row-major with alpha (halves score traffic)
    unsigned short* C = (unsigned short*)Cv + (long long)bz*sC;
#pragma unroll
    for (int mf = 0; mf < 4; mf++)
#pragma unroll
      for (int r = 0; r < 4; r++) {
        const int row = m0 + mf*16 + lg*4 + r;
#pragma unroll
        for (int nf = 0; nf < 4; nf++)
          C[(long long)row*ldc + n0 + nf*16 + lr] = f2bf(acc[mf][nf][r] * alpha);
      }
  }
}

__global__ __launch_bounds__(256) void qkv_k(
    const unsigned short* __restrict__ Wqkv, const unsigned short* __restrict__ xb,
    unsigned short* __restrict__ Qu, const float* __restrict__ biasQKV)
{
  gemm_nt_body<1>(Wqkv, xb, (void*)Qu, biasQKV, 768, 4096, 256, 256, 256, 0,
                  0, 1048576, 0, 1.0f, blockIdx.x, blockIdx.y, blockIdx.z);
}

// ====================== scale-0 scores: wave-per (b,ks) ====================
__device__ void s0_scores_wave(
    const unsigned short* __restrict__ Q, const unsigned short* __restrict__ K,
    float* __restrict__ Sp, int bid)
{
  const int t = threadIdx.x, l = t & 63, w = t >> 6;
  const int lr = l & 15, lg = l >> 4;
  const int task = bid*4 + w;
  const int b = task >> 3, ks = task & 7;
  const unsigned short* Qb = Q + (long long)b*262144;
  const unsigned short* Kb = K + (long long)b*262144;
  f32x4 acc[4][4] = {};
  const int k0 = ks*512;
#pragma unroll 2
  for (int kk = k0; kk < k0 + 512; kk += 32) {
    short8 af[4], bf[4];
#pragma unroll
    for (int i = 0; i < 4; i++)
      af[i] = *(const short8*)(Qb + (long long)(i*16 + lr)*4096 + kk + lg*8);
#pragma unroll
    for (int i = 0; i < 4; i++)
      bf[i] = *(const short8*)(Kb + (long long)(i*16 + lr)*4096 + kk + lg*8);
#pragma unroll
    for (int mf = 0; mf < 4; mf++)
#pragma unroll
      for (int nf = 0; nf < 4; nf++)
        acc[mf][nf] = __builtin_amdgcn_mfma_f32_16x16x32_bf16(
            af[mf], bf[nf], acc[mf][nf], 0, 0, 0);
  }
#pragma unroll
  for (int mf = 0; mf < 4; mf++)
#pragma unroll
    for (int r = 0; r < 4; r++) {
      const int row = mf*16 + lg*4 + r;
#pragma unroll
      for (int nf = 0; nf < 4; nf++)
        Sp[(((long long)(ks*4 + b)*64 + row) << 6) + nf*16 + lr]
            = acc[mf][nf][r];
    }
}

// ====================== scale-3 flash body (dbuf, static-max) ==============
// r8/r12/r14-measured best (~73us inside stageA). No KV split, dbuf LDS,
// direct bf16 NHWC output (ch 192..255). Lane owns ONE query (q = w*16+lr).
__device__ void flash3_body(
    const unsigned short* __restrict__ Q3, const unsigned short* __restrict__ K3,
    const unsigned short* __restrict__ Vt3, unsigned short* __restrict__ inb,
    int bx, int b)
{
  constexpr int LD = 72;
  __shared__ unsigned short KVs[2][2][64*LD];   // [buf][K|V][.]
  __shared__ unsigned short Ps[64*LD];
  const int t = threadIdx.x, l = t & 63, w = t >> 6;
  const int lr = l & 15, lg = l >> 4;
  const int q0 = bx * 64;
  const long long base = (long long)b * 262144;
  const unsigned short* Qg = Q3 + base;   // [n][d]
  const unsigned short* Kg = K3 + base;   // [n][d]
  const unsigned short* Vg = Vt3 + base;  // [d][n]

  short8 bq[2];
  bq[0] = *(const short8*)(Qg + (long long)(q0 + w*16 + lr)*64 + lg*8);
  bq[1] = *(const short8*)(Qg + (long long)(q0 + w*16 + lr)*64 + 32 + lg*8);

  f32x4 acc[4] = {};
  float li = 0.f;

  const int r_ = t >> 3, c8_ = (t & 7) * 8;
  uint4 kreg[2], vreg[2];

#define LOADKV(KT) do { \
    const int k0_ = (KT) * 64; \
    _Pragma("unroll") \
    for (int it = 0; it < 2; it++) { \
      const int rr = r_ + it*32; \
      kreg[it] = *(const uint4*)(Kg + (long long)(k0_ + rr)*64 + c8_); \
      vreg[it] = *(const uint4*)(Vg + (long long)rr*4096 + k0_ + c8_); \
    } } while (0)
#define STOREKV(BUF) do { \
    _Pragma("unroll") \
    for (int it = 0; it < 2; it++) { \
      const int rr = r_ + it*32; \
      *(uint4*)(KVs[BUF][0] + rr*LD + c8_) = kreg[it]; \
      *(uint4*)(KVs[BUF][1] + rr*LD + c8_) = vreg[it]; \
    } } while (0)

  LOADKV(0);
  STOREKV(0);
  __syncthreads();

  for (int kt = 0; kt < 64; ++kt) {
    if (kt < 63) LOADKV(kt + 1);
    const unsigned short* Ksb = KVs[kt & 1][0];
    const unsigned short* Vsb = KVs[kt & 1][1];
    // S^T[key][q]
    f32x4 s[4];
#pragma unroll
    for (int cf = 0; cf < 4; cf++) {
      short8 ak0 = *(const short8*)(Ksb + (cf*16 + lr)*LD + lg*8);
      short8 ak1 = *(const short8*)(Ksb + (cf*16 + lr)*LD + 32 + lg*8);
      f32x4 zz = {};
      zz = __builtin_amdgcn_mfma_f32_16x16x32_bf16(ak0, bq[0], zz, 0,0,0);
      s[cf] = __builtin_amdgcn_mfma_f32_16x16x32_bf16(ak1, bq[1], zz, 0,0,0);
    }
    // static-max softmax (scores bounded; no max tracking, no cross-lane)
    float p[16], psum = 0.f;
#pragma unroll
    for (int cf = 0; cf < 4; cf++)
#pragma unroll
      for (int r = 0; r < 4; r++) {
        float e = exp2f(fmaf(s[cf][r], FC, -CSHIFT));
        p[cf*4 + r] = e; psum += e;
      }
    li += psum;
    {
      unsigned short* pr = Ps + (w*16 + lr)*LD;
#pragma unroll
      for (int cf = 0; cf < 4; cf++) {
        *(unsigned*)(pr + cf*16 + lg*4)     = cvt_pk_bf16(p[cf*4+0], p[cf*4+1]);
        *(unsigned*)(pr + cf*16 + lg*4 + 2) = cvt_pk_bf16(p[cf*4+2], p[cf*4+3]);
      }
    }
    short8 bp0 = *(const short8*)(Ps + (w*16 + lr)*LD + lg*8);
    short8 bp1 = *(const short8*)(Ps + (w*16 + lr)*LD + 32 + lg*8);
#pragma unroll
    for (int df = 0; df < 4; df++) {
      short8 av0 = *(const short8*)(Vsb + (df*16 + lr)*LD + lg*8);
      short8 av1 = *(const short8*)(Vsb + (df*16 + lr)*LD + 32 + lg*8);
      acc[df] = __builtin_amdgcn_mfma_f32_16x16x32_bf16(av0, bp0, acc[df], 0,0,0);
      acc[df] = __builtin_amdgcn_mfma_f32_16x16x32_bf16(av1, bp1, acc[df], 0,0,0);
    }
    if (kt < 63) {
      STOREKV((kt + 1) & 1);
      __syncthreads();     // one barrier/tile; dbuf keeps phases disjoint
    }
  }
#undef LOADKV
#undef STOREKV
  li += __shfl_xor(li, 16);
  li += __shfl_xor(li, 32);
  const float inv = 1.f / li;
  const long long row = (long long)b*4096 + q0 + w*16 + lr;
  unsigned short* ob = inb + row*256 + 192 + lg*4;
#pragma unroll
  for (int df = 0; df < 4; df++) {
    *(unsigned*)(ob + df*16)     = cvt_pk_bf16(acc[df][0]*inv, acc[df][1]*inv);
    *(unsigned*)(ob + df*16 + 2) = cvt_pk_bf16(acc[df][2]*inv, acc[df][3]*inv);
  }
}

// ====================== stage A: flash3 + all scores =======================
__global__ __launch_bounds__(256) void stageA_k(
    const unsigned short* __restrict__ Qu, const unsigned short* __restrict__ Ku,
    const unsigned short* __restrict__ Vu,
    float* __restrict__ Sp0, unsigned short* __restrict__ S1,
    unsigned short* __restrict__ S2, unsigned short* __restrict__ inb)
{
  const int bid = blockIdx.x;
  if (bid < 256) {                       // flash3 (longest) first
    flash3_body(Qu+3145728, Ku+3145728, Vu+3145728, inb, bid & 63, bid >> 6);
  } else if (bid < 264) {                // s0 scores: 8 blocks, wave tasks
    s0_scores_wave(Qu, Ku, Sp0, bid - 256);
  } else if (bid < 280) {                // s1 scores (bf16 out): grid (2,2,4)
    int q = bid - 264;
    gemm_nt_body<3>(Qu+1048576, Ku+1048576, (void*)S1, nullptr,
        256, 256, 1024, 1024, 1024, 256, 262144, 262144, 65536, 0.03125f,
        q & 1, (q >> 1) & 1, q >> 2);
  } else {                               // s2 scores (bf16 out): grid (8,8,4)
    int q = bid - 280;
    gemm_nt_body<3>(Qu+2097152, Ku+2097152, (void*)S2, nullptr,
        1024, 1024, 256, 256, 256, 1024, 262144, 262144, 1048576, 0.0625f,
        q & 7, (q >> 3) & 7, q >> 6);
  }
}

// ====================== stage B: all softmaxes =============================
// Vectorized bf16-input softmax: lane l owns CNT contiguous elements.
template<int CNT>
__device__ void softmax_row_bf(const unsigned short* __restrict__ S,
                               unsigned short* __restrict__ P, long long row)
{
  const int l = threadIdx.x & 63;
  const unsigned short* p = S + row*(CNT*64) + l*CNT;
  unsigned short* o = P + row*(CNT*64) + l*CNT;
  float v[CNT];
#pragma unroll
  for (int i = 0; i < CNT; i += 4) {
    ushort4 u = *(const ushort4*)(p + i);
    v[i] = bf2f(u.x); v[i+1] = bf2f(u.y); v[i+2] = bf2f(u.z); v[i+3] = bf2f(u.w);
  }
  float mx = v[0];
#pragma unroll
  for (int i = 1; i < CNT; i++) mx = fmaxf(mx, v[i]);
#pragma unroll
  for (int off = 1; off < 64; off <<= 1) mx = fmaxf(mx, __shfl_xor(mx, off, 64));
  float sum = 0.f;
#pragma unroll
  for (int i = 0; i < CNT; i++) { v[i] = __expf(v[i] - mx); sum += v[i]; }
#pragma unroll
  for (int off = 1; off < 64; off <<= 1) sum += __shfl_xor(sum, off, 64);
  const float inv = 1.f / sum;
#pragma unroll
  for (int i = 0; i < CNT; i += 4) {
    unsigned w0 = cvt_pk_bf16(v[i]*inv,   v[i+1]*inv);
    unsigned w1 = cvt_pk_bf16(v[i+2]*inv, v[i+3]*inv);
    *(uint2*)(o + i) = make_uint2(w0, w1);
  }
}

__global__ __launch_bounds__(256) void stageB_k(
    const float* __restrict__ Sp0, unsigned short* __restrict__ P0,
    const unsigned short* __restrict__ S1, unsigned short* __restrict__ P1,
    const unsigned short* __restrict__ S2, unsigned short* __restrict__ P2)
{
  const int bid = blockIdx.x, t = threadIdx.x, l = t & 63, w = t >> 6;
  if (bid < 1024) {                      // s2: 4096 rows, CNT=16
    softmax_row_bf<16>(S2, P2, (long long)bid*4 + w);
  } else if (bid < 1280) {               // s1: 1024 rows, CNT=4
    softmax_row_bf<4>(S1, P1, (long long)(bid - 1024)*4 + w);
  } else {                               // s0: reduce 8 partials + softmax
    const int row = (bid - 1280)*4 + w;  // < 256
    const int b = row >> 6, r = row & 63;
    float v = 0.f;
#pragma unroll
    for (int ks = 0; ks < 8; ks++)
      v += Sp0[(((long long)(ks*4 + b)*64 + r) << 6) + l];
    v *= 0.015625f;
    float mx = v;
#pragma unroll
    for (int off = 1; off < 64; off <<= 1) mx = fmaxf(mx, __shfl_xor(mx, off, 64));
    float e = __expf(v - mx), sum = e;
#pragma unroll
    for (int off = 1; off < 64; off <<= 1) sum += __shfl_xor(sum, off, 64);
    P0[(row << 6) + l] = f2bf(e / sum);
  }
}

// ====================== stage C: all PV GEMMs -> bf16 NHWC =================
__global__ __launch_bounds__(256) void stageC_k(
    const unsigned short* __restrict__ P0, const unsigned short* __restrict__ P1,
    const unsigned short* __restrict__ P2, const unsigned short* __restrict__ Vu,
    unsigned short* __restrict__ inb)
{
  const int bid = blockIdx.x;
  if (bid < 128) {                       // s0 PV: grid (32,1,4), scale 0
    int q = bid;
    gemm_nt_body<2,3>(P0, Vu, (void*)inb, nullptr,
        64, 4096, 64, 64, 64, 0, 4096, 262144, 0, 1.0f,
        q & 31, 0, q >> 5);
  } else if (bid < 192) {                // s1 PV: grid (8,2,4), scale 1
    int q = bid - 128;
    gemm_nt_body<2,2>(P1, Vu+1048576, (void*)inb, nullptr,
        256, 1024, 256, 256, 256, 0, 65536, 262144, 0, 1.0f,
        q & 7, (q >> 3) & 1, q >> 4);
  } else {                               // s2 PV: grid (2,8,4), scale 2
    int q = bid - 192;
    gemm_nt_body<2,1>(P2, Vu+2097152, (void*)inb, nullptr,
        1024, 256, 1024, 1024, 1024, 0, 1048576, 262144, 0, 1.0f,
        q & 1, (q >> 1) & 7, q >> 4);
  }
}

// ====================== 3x3 conv: dbuf + reg-stage + A-preload =============
// Writes z as bf16 (halves conv write + both BN read legs).
__global__ __launch_bounds__(512) void conv_mfma_k(
    const unsigned short* __restrict__ inb, const unsigned short* __restrict__ Wb,
    const float* __restrict__ bias, unsigned short* __restrict__ zb)
{
  __shared__ unsigned short lds[2][6*66*32];   // 2 x 25,344 B
  const int t = threadIdx.x;
  const int l = t & 63, wid = t >> 6;          // 8 waves
  const int lr = l & 15, lg = l >> 4;
  const int waveM = wid >> 2, waveN = wid & 3;
  const int b = blockIdx.x >> 4, y0 = (blockIdx.x & 15) * 4;
  const int oc0 = blockIdx.y * 64 + waveM * 32;
  const long long inbase = (long long)b * 1048576;
  const int kgrp = lg * 8;

  f32x4 acc[2][4] = {};
  uint4 sreg[4];

#define CLOAD(IC0) do { \
    _Pragma("unroll") \
    for (int i = 0; i < 4; i++) { \
      int q = t + i*512; \
      if (q < 1584) { \
        int ic8 = q & 3, cc = (q >> 2) % 66, rr = q / 264; \
        int gy = y0 - 1 + rr, gx = cc - 1; \
        uint4 v = make_uint4(0u,0u,0u,0u); \
        if ((unsigned)gy < 64u && (unsigned)gx < 64u) \
          v = *(const uint4*)(inb + inbase + ((long long)(gy*64+gx))*256 \
                              + (IC0) + ic8*8); \
        sreg[i] = v; \
      } \
    } } while (0)
#define CSTORE(BUF) do { \
    _Pragma("unroll") \
    for (int i = 0; i < 4; i++) { \
      int q = t + i*512; \
      if (q < 1584) *(uint4*)(&lds[BUF][q*8]) = sreg[i]; \
    } } while (0)

  CLOAD(0);
  CSTORE(0);
  __syncthreads();

  for (int c = 0; c < 8; ++c) {
    const int ic0 = c * 32;
    if (c < 7) CLOAD(ic0 + 32);
    const unsigned short* wbase = Wb + (long long)(oc0 + lr)*256 + ic0 + kgrp;
    short8 afr[9][2];
#pragma unroll
    for (int tap = 0; tap < 9; tap++) {
      afr[tap][0] = *(const short8*)(wbase + (long long)tap*65536);
      afr[tap][1] = *(const short8*)(wbase + (long long)tap*65536 + 16*256);
    }
    const unsigned short* L = lds[c & 1];
#pragma unroll
    for (int ky = 0; ky < 3; ky++) {
#pragma unroll
      for (int kx = 0; kx < 3; kx++) {
        const int tap = ky*3 + kx;
#pragma unroll
        for (int nf = 0; nf < 4; nf++) {
          int pix = waveN*64 + nf*16 + lr;
          int rp = pix >> 6, xx = pix & 63;
          short8 bf = *(const short8*)(L + ((rp + ky)*66 + xx + kx)*32 + kgrp);
          acc[0][nf] = __builtin_amdgcn_mfma_f32_16x16x32_bf16(
              afr[tap][0], bf, acc[0][nf], 0, 0, 0);
          acc[1][nf] = __builtin_amdgcn_mfma_f32_16x16x32_bf16(
              afr[tap][1], bf, acc[1][nf], 0, 0, 0);
        }
      }
    }
    if (c < 7) {
      CSTORE((c + 1) & 1);
      __syncthreads();
    }
  }
#undef CLOAD
#undef CSTORE

  const long long zbase = ((long long)b * 256) << 12;
#pragma unroll
  for (int mf = 0; mf < 2; mf++) {
#pragma unroll
    for (int r = 0; r < 4; r++) {
      const int oc = oc0 + mf*16 + lg*4 + r;
      const float bb = bias[oc];
      const long long rowbase = zbase + ((long long)oc << 12) + y0*64;
#pragma unroll
      for (int nf = 0; nf < 4; nf++) {
        int pix = waveN*64 + nf*16 + lr;
        zb[rowbase + pix] = f2bf(acc[mf][nf][r] + bb);
      }
    }
  }
}

// ====================== BatchNorm + LeakyReLU (bf16 z) =====================
__global__ __launch_bounds__(256) void bn_stats_k(
    const unsigned short* __restrict__ zb, float* __restrict__ stats)
{
  const int ch = blockIdx.x, t = threadIdx.x;
  float s = 0.f, q = 0.f;
  for (int b = 0; b < 4; b++) {
    const unsigned short* p = zb + ((long long)(b*256 + ch) << 12);
    for (int i = t; i < 512; i += 256) {    // 512 x 8 bf16 = 4096 elems
      short8 v8 = *(const short8*)(p + i*8);
#pragma unroll
      for (int j = 0; j < 8; j++) {
        float v = bf2f((unsigned short)v8[j]);
        s += v; q += v*v;
      }
    }
  }
  __shared__ float rs[256], rq[256];
  rs[t] = s; rq[t] = q; __syncthreads();
  for (int st = 128; st > 0; st >>= 1) {
    if (t < st) { rs[t] += rs[t+st]; rq[t] += rq[t+st]; }
    __syncthreads();
  }
  if (t == 0) {
    float mean = rs[0] * (1.f/16384.f);
    float var  = rq[0] * (1.f/16384.f) - mean*mean;
    stats[ch]       = mean;
    stats[256 + ch] = rsqrtf(var + 1e-5f);
  }
}

__global__ __launch_bounds__(256) void bn_apply_k(
    const unsigned short* __restrict__ zb, const float* __restrict__ stats,
    const float* __restrict__ gamma, const float* __restrict__ beta,
    float* __restrict__ out)
{
  long long i4 = ((long long)blockIdx.x*256 + threadIdx.x) * 4;
  int ch = (int)((i4 >> 12) & 255);
  float mean = stats[ch], rsg = stats[256 + ch];
  float g = gamma[ch], bt = beta[ch];
  ushort4 v = *(const ushort4*)(zb + i4);
  float r[4] = {bf2f(v.x), bf2f(v.y), bf2f(v.z), bf2f(v.w)};
#pragma unroll
  for (int j = 0; j < 4; j++) {
    float u = (r[j] - mean) * rsg * g + bt;
    r[j] = u > 0.f ? u : 0.2f * u;
  }
  *(float4*)(out + i4) = make_float4(r[0], r[1], r[2], r[3]);
}

// ---------------------------------------------------------------------------
extern "C" void kernel_launch(void* const* d_in, const int* in_sizes, int n_in,
                              void* d_out, int out_size, void* d_ws, size_t ws_size,
                              hipStream_t stream)
{
  const float* x     = (const float*)d_in[0];
  const float* wq    = (const float*)d_in[1];
  const float* bq    = (const float*)d_in[2];
  const float* wk    = (const float*)d_in[3];
  const float* bk    = (const float*)d_in[4];
  const float* wv    = (const float*)d_in[5];
  const float* bv    = (const float*)d_in[6];
  const float* w_out = (const float*)d_in[7];
  const float* b_out = (const float*)d_in[8];
  const float* gamma = (const float*)d_in[9];
  const float* beta  = (const float*)d_in[10];
  float* out = (float*)d_out;

  float* ws = (float*)d_ws;
  unsigned short* xb  = (unsigned short*)(ws + OFF_XB);
  unsigned short* Qu  = (unsigned short*)(ws + OFF_QB);
  unsigned short* Ku  = Qu + 4194304;
  unsigned short* Vu  = Qu + 8388608;
  unsigned short* S2b = (unsigned short*)(ws + OFF_SS);
  unsigned short* P2 = (unsigned short*)(ws + OFF_PP);
  unsigned short* Wqk = (unsigned short*)(ws + OFF_WQK);
  float* biasQ = ws + OFF_BIA;
  unsigned short* Wcv = (unsigned short*)(ws + OFF_WCV);
  float* St  = ws + OFF_STT;
  float* Sp0 = ws + OFF_SP0;
  unsigned short* S1b = (unsigned short*)(ws + OFF_S1);
  unsigned short* P0 = (unsigned short*)(ws + OFF_P0);
  unsigned short* P1 = (unsigned short*)(ws + OFF_P1);
  unsigned short* inb = (unsigned short*)(ws + OFF_XB);   // alias: xb dead
  unsigned short* zb  = (unsigned short*)(ws + OFF_YT);   // conv out bf16

  dim3 blk(256);

  // 1) prep: x transpose + all weight conversions
  prep_k<<<dim3(3328), blk, 0, stream>>>(
      x, xb, wq, wk, wv, bq, bk, bv, Wqk, biasQ, w_out, Wcv);

  // 2) fused QKV projection -> bf16 token layouts (V transposed)
  qkv_k<<<dim3(32,6,4), blk, 0, stream>>>(Wqk, xb, Qu, biasQ);

  // 3) stage A: flash3 (no-split, dbuf, direct NHWC) + all scores (bf16)
  stageA_k<<<dim3(536), blk, 0, stream>>>(Qu, Ku, Vu, Sp0, S1b, S2b, inb);

  // 4) stage B: all softmaxes (bf16 in, vectorized)
  stageB_k<<<dim3(1344), blk, 0, stream>>>(Sp0, P0, S1b, P1, S2b, P2);

  // 5) stage C: all PV GEMMs -> bf16 NHWC (ch 0-191)
  stageC_k<<<dim3(256), blk, 0, stream>>>(P0, P1, P2, Vu, inb);

  // 6) 3x3 conv (dbuf, 8 waves) -> bf16 z
  conv_mfma_k<<<dim3(64,4), dim3(512), 0, stream>>>(inb, Wcv, b_out, zb);

  // 7) BN + LeakyReLU (bf16 z)
  bn_stats_k<<<dim3(256), blk, 0, stream>>>(zb, St);
  bn_apply_k<<<dim3(4096), blk, 0, stream>>>(zb, St, gamma, beta, out);
}

// Round 19
// 221.041 us; speedup vs baseline: 1.1319x; 1.1319x over previous
//
#include <hip/hip_runtime.h>
#include <cmath>

// ---------------------------------------------------------------------------
// Workspace layout (float offsets). Total 19,801,344 floats ~= 79.2 MB.
//  XB  = 0          xb bf16 [4][4096 pix][256 c]   (later: inb conv input)
//  QB  = 2,097,152  Q tokens bf16 [n][d]
//  KB  = 4,194,304  K tokens bf16 [n][d]
//  VB  = 6,291,456  V^T tokens bf16, 4 scales x [4][D][N]
//  SS  = 8,388,608  S2 scores fp32 [4][1024][1024]
//  PP  = 12,582,912 P2 bf16 [4][1024][1024]
//  YT  = 14,680,064 conv out z bf16 [4][256][64][64]
//  WQK = 18,874,368 Wqkv bf16 [768][256]
//  BIA = 18,972,672 stacked qkv bias fp32 [768]
//  WCV = 18,973,440 conv weights bf16 [9][256][256]
//  STT = 19,268,352 bn stats [512]
//  SP0 = 19,268,864 s0 score partials [32][64][64] fp32
//  S1  = 19,399,936 s1 scores fp32 [4][256][256]
//  P0  = 19,662,080 s0 P bf16 (16384 ush)
//  P1  = 19,670,272 s1 P bf16 (262144 ush)
// ---------------------------------------------------------------------------

#define OFF_XB  0LL
#define OFF_QB  2097152LL
#define OFF_SS  8388608LL
#define OFF_PP  12582912LL
#define OFF_YT  14680064LL
#define OFF_WQK 18874368LL
#define OFF_BIA 18972672LL
#define OFF_WCV 18973440LL
#define OFF_STT 19268352LL
#define OFF_SP0 19268864LL
#define OFF_S1  19399936LL
#define OFF_P0  19662080LL
#define OFF_P1  19670272LL

#define FC 0.18033688f   // 0.125 * log2(e)
#define CSHIFT 6.0f      // static softmax shift (exp2 domain)

typedef __attribute__((ext_vector_type(8))) short short8;
typedef __attribute__((ext_vector_type(4))) float f32x4;

__device__ inline unsigned short f2bf(float f) {
  unsigned u = __float_as_uint(f);
  u += 0x7fff + ((u >> 16) & 1);
  return (unsigned short)(u >> 16);
}

__device__ inline float bf2f(unsigned short h) {
  return __uint_as_float((unsigned)h << 16);
}

__device__ inline unsigned cvt_pk_bf16(float a, float b) {
  unsigned r;
  asm("v_cvt_pk_bf16_f32 %0, %1, %2" : "=v"(r) : "v"(a), "v"(b));
  return r;   // lo16 = bf16(a), hi16 = bf16(b)
}

// ====================== merged prep: xpose + wcvt + wconv ==================
__global__ __launch_bounds__(256) void prep_k(
    const float* __restrict__ x, unsigned short* __restrict__ xb,
    const float* __restrict__ wq, const float* __restrict__ wk,
    const float* __restrict__ wv, const float* __restrict__ bq,
    const float* __restrict__ bk, const float* __restrict__ bv,
    unsigned short* __restrict__ Wqkv, float* __restrict__ biasQKV,
    const float* __restrict__ wcv, unsigned short* __restrict__ Wcb)
{
  const int bid = blockIdx.x, t = threadIdx.x;
  if (bid < 256) {
    __shared__ unsigned short rowb[256][66];
    const int b = bid >> 6, y = bid & 63;
    for (int i = t; i < 16384; i += 256) {
      int c = i >> 6, xx = i & 63;
      rowb[c][xx] = f2bf(x[((long long)(b*256 + c) << 12) + (y << 6) + xx]);
    }
    __syncthreads();
    unsigned int* outw = (unsigned int*)(xb + ((long long)bid << 14));
    for (int i = t; i < 8192; i += 256) {
      int xx = i >> 7, c2 = (i & 127) * 2;
      outw[xx*128 + (c2 >> 1)] = (unsigned)rowb[c2][xx]
                               | ((unsigned)rowb[c2+1][xx] << 16);
    }
  } else if (bid < 1024) {
    const int row = bid - 256;
    const int which = row >> 8, oc = row & 255;
    const float* src = which == 0 ? wq : which == 1 ? wk : wv;
    Wqkv[row*256 + t] = f2bf(src[oc*256 + t]);
    if (row < 3) {
      const float* bs = row == 0 ? bq : row == 1 ? bk : bv;
      biasQKV[row*256 + t] = bs[t];
    }
  } else {
    int i = (bid - 1024)*256 + t;    // < 589824
    int tap = i >> 16, oc = (i >> 8) & 255, ic = i & 255;
    Wcb[i] = f2bf(wcv[((long long)(oc*256 + ic))*9 + tap]);
  }
}

// ====================== bf16 MFMA NT GEMM body (no LDS) ====================
// EPI 0: fp32 C row-major.   EPI 1: QKV token scatter (bf16 + bias).
// EPI 2: PV -> bf16 NHWC scatter (row=token, col=dim, scale = 3-SH).
template<int EPI, int SH = 0>
__device__ void gemm_nt_body(
    const unsigned short* __restrict__ A, const unsigned short* __restrict__ B,
    void* __restrict__ Cv, const float* __restrict__ bias,
    int M, int N, int K, int lda, int ldb, int ldc,
    long long sA, long long sB, long long sC, float alpha,
    int bx, int by, int bz)
{
  const int t = threadIdx.x, l = t & 63;
  const int lr = l & 15, lg = l >> 4;
  const int w = t >> 6, wm = w >> 1, wn = w & 1;
  const int m0 = by*128 + wm*64, n0 = bx*128 + wn*64;
  if (m0 >= M || n0 >= N) return;
  const unsigned short* Ab = A + (long long)bz*sA + (long long)(m0 + lr)*lda + lg*8;
  const unsigned short* Bb = B + (long long)bz*sB + (long long)(n0 + lr)*ldb + lg*8;

  f32x4 acc[4][4] = {};
#pragma unroll 2
  for (int kk = 0; kk < K; kk += 32) {
    short8 af[4], bf[4];
#pragma unroll
    for (int i = 0; i < 4; i++)
      af[i] = *(const short8*)(Ab + (long long)i*16*lda + kk);
#pragma unroll
    for (int i = 0; i < 4; i++)
      bf[i] = *(const short8*)(Bb + (long long)i*16*ldb + kk);
#pragma unroll
    for (int mf = 0; mf < 4; mf++)
#pragma unroll
      for (int nf = 0; nf < 4; nf++)
        acc[mf][nf] = __builtin_amdgcn_mfma_f32_16x16x32_bf16(
            af[mf], bf[nf], acc[mf][nf], 0, 0, 0);
  }

  if (EPI == 0) {
    float* C = (float*)Cv + (long long)bz*sC;
#pragma unroll
    for (int mf = 0; mf < 4; mf++)
#pragma unroll
      for (int r = 0; r < 4; r++) {
        const int row = m0 + mf*16 + lg*4 + r;
#pragma unroll
        for (int nf = 0; nf < 4; nf++)
          C[(long long)row*ldc + n0 + nf*16 + lr] = acc[mf][nf][r] * alpha;
      }
  } else if (EPI == 1) {
    unsigned short* Qbase = (unsigned short*)Cv;
#pragma unroll
    for (int mf = 0; mf < 4; mf++)
#pragma unroll
      for (int r = 0; r < 4; r++) {
        const int gi = m0 + mf*16 + lg*4 + r;          // 0..767
        const int which = gi >> 8, ch = gi & 255;
        const int scale = ch >> 6, c = ch & 63;
        const int sh = 3 - scale, msk = (1 << sh) - 1;
        const bool tr = (which == 2);                  // only V transposed
        const float bb = bias[gi];
        unsigned short* dst = Qbase + (long long)which*4194304
                            + (long long)scale*1048576 + (long long)bz*262144;
#pragma unroll
        for (int nf = 0; nf < 4; nf++) {
          const int gj = n0 + nf*16 + lr;              // pixel
          const int y = gj >> 6, xx = gj & 63;
          const int n = (y >> sh)*(64 >> sh) + (xx >> sh);
          const int d = (c << (2*sh)) + ((y & msk) << sh) + (xx & msk);
          const long long idx = tr
              ? (long long)d*(4096 >> (2*sh)) + n      // [d][n]
              : (long long)n*(64 << (2*sh)) + d;       // [n][d]
          dst[idx] = f2bf(acc[mf][nf][r] + bb);
        }
      }
  } else {
    // EPI 2: token/dim -> bf16 NHWC (channels (3-SH)*64 .. +63)
    unsigned short* inb = (unsigned short*)Cv;
    constexpr int msk = (1 << SH) - 1;
    constexpr int scale = 3 - SH;
#pragma unroll
    for (int mf = 0; mf < 4; mf++)
#pragma unroll
      for (int r = 0; r < 4; r++) {
        const int gi = m0 + mf*16 + lg*4 + r;          // token n
        const int ty = gi >> (6 - SH), tx = gi & ((64 >> SH) - 1);
#pragma unroll
        for (int nf = 0; nf < 4; nf++) {
          const int gj = n0 + nf*16 + lr;              // dim d
          const int c = gj >> (2*SH);
          const int y = (ty << SH) | ((gj >> SH) & msk);
          const int x = (tx << SH) | (gj & msk);
          inb[((((long long)bz << 12) + (y << 6) + x) << 8) + scale*64 + c]
              = f2bf(acc[mf][nf][r]);
        }
      }
  }
}

__global__ __launch_bounds__(256) void qkv_k(
    const unsigned short* __restrict__ Wqkv, const unsigned short* __restrict__ xb,
    unsigned short* __restrict__ Qu, const float* __restrict__ biasQKV)
{
  gemm_nt_body<1>(Wqkv, xb, (void*)Qu, biasQKV, 768, 4096, 256, 256, 256, 0,
                  0, 1048576, 0, 1.0f, blockIdx.x, blockIdx.y, blockIdx.z);
}

// ====================== scale-0 scores: wave-per (b,ks) ====================
__device__ void s0_scores_wave(
    const unsigned short* __restrict__ Q, const unsigned short* __restrict__ K,
    float* __restrict__ Sp, int bid)
{
  const int t = threadIdx.x, l = t & 63, w = t >> 6;
  const int lr = l & 15, lg = l >> 4;
  const int task = bid*4 + w;
  const int b = task >> 3, ks = task & 7;
  const unsigned short* Qb = Q + (long long)b*262144;
  const unsigned short* Kb = K + (long long)b*262144;
  f32x4 acc[4][4] = {};
  const int k0 = ks*512;
#pragma unroll 2
  for (int kk = k0; kk < k0 + 512; kk += 32) {
    short8 af[4], bf[4];
#pragma unroll
    for (int i = 0; i < 4; i++)
      af[i] = *(const short8*)(Qb + (long long)(i*16 + lr)*4096 + kk + lg*8);
#pragma unroll
    for (int i = 0; i < 4; i++)
      bf[i] = *(const short8*)(Kb + (long long)(i*16 + lr)*4096 + kk + lg*8);
#pragma unroll
    for (int mf = 0; mf < 4; mf++)
#pragma unroll
      for (int nf = 0; nf < 4; nf++)
        acc[mf][nf] = __builtin_amdgcn_mfma_f32_16x16x32_bf16(
            af[mf], bf[nf], acc[mf][nf], 0, 0, 0);
  }
#pragma unroll
  for (int mf = 0; mf < 4; mf++)
#pragma unroll
    for (int r = 0; r < 4; r++) {
      const int row = mf*16 + lg*4 + r;
#pragma unroll
      for (int nf = 0; nf < 4; nf++)
        Sp[(((long long)(ks*4 + b)*64 + row) << 6) + nf*16 + lr]
            = acc[mf][nf][r];
    }
}

// ====================== scale-3 flash body (dbuf, static-max) ==============
// r8/r12/r14-measured best (~73us inside stageA). No KV split, dbuf LDS,
// direct bf16 NHWC output (ch 192..255). Lane owns ONE query (q = w*16+lr).
__device__ void flash3_body(
    const unsigned short* __restrict__ Q3, const unsigned short* __restrict__ K3,
    const unsigned short* __restrict__ Vt3, unsigned short* __restrict__ inb,
    int bx, int b)
{
  constexpr int LD = 72;
  __shared__ unsigned short KVs[2][2][64*LD];   // [buf][K|V][.]
  __shared__ unsigned short Ps[64*LD];
  const int t = threadIdx.x, l = t & 63, w = t >> 6;
  const int lr = l & 15, lg = l >> 4;
  const int q0 = bx * 64;
  const long long base = (long long)b * 262144;
  const unsigned short* Qg = Q3 + base;   // [n][d]
  const unsigned short* Kg = K3 + base;   // [n][d]
  const unsigned short* Vg = Vt3 + base;  // [d][n]

  short8 bq[2];
  bq[0] = *(const short8*)(Qg + (long long)(q0 + w*16 + lr)*64 + lg*8);
  bq[1] = *(const short8*)(Qg + (long long)(q0 + w*16 + lr)*64 + 32 + lg*8);

  f32x4 acc[4] = {};
  float li = 0.f;

  const int r_ = t >> 3, c8_ = (t & 7) * 8;
  uint4 kreg[2], vreg[2];

#define LOADKV(KT) do { \
    const int k0_ = (KT) * 64; \
    _Pragma("unroll") \
    for (int it = 0; it < 2; it++) { \
      const int rr = r_ + it*32; \
      kreg[it] = *(const uint4*)(Kg + (long long)(k0_ + rr)*64 + c8_); \
      vreg[it] = *(const uint4*)(Vg + (long long)rr*4096 + k0_ + c8_); \
    } } while (0)
#define STOREKV(BUF) do { \
    _Pragma("unroll") \
    for (int it = 0; it < 2; it++) { \
      const int rr = r_ + it*32; \
      *(uint4*)(KVs[BUF][0] + rr*LD + c8_) = kreg[it]; \
      *(uint4*)(KVs[BUF][1] + rr*LD + c8_) = vreg[it]; \
    } } while (0)

  LOADKV(0);
  STOREKV(0);
  __syncthreads();

  for (int kt = 0; kt < 64; ++kt) {
    if (kt < 63) LOADKV(kt + 1);
    const unsigned short* Ksb = KVs[kt & 1][0];
    const unsigned short* Vsb = KVs[kt & 1][1];
    // S^T[key][q]
    f32x4 s[4];
#pragma unroll
    for (int cf = 0; cf < 4; cf++) {
      short8 ak0 = *(const short8*)(Ksb + (cf*16 + lr)*LD + lg*8);
      short8 ak1 = *(const short8*)(Ksb + (cf*16 + lr)*LD + 32 + lg*8);
      f32x4 zz = {};
      zz = __builtin_amdgcn_mfma_f32_16x16x32_bf16(ak0, bq[0], zz, 0,0,0);
      s[cf] = __builtin_amdgcn_mfma_f32_16x16x32_bf16(ak1, bq[1], zz, 0,0,0);
    }
    // static-max softmax (scores bounded; no max tracking, no cross-lane)
    float p[16], psum = 0.f;
#pragma unroll
    for (int cf = 0; cf < 4; cf++)
#pragma unroll
      for (int r = 0; r < 4; r++) {
        float e = exp2f(fmaf(s[cf][r], FC, -CSHIFT));
        p[cf*4 + r] = e; psum += e;
      }
    li += psum;
    {
      unsigned short* pr = Ps + (w*16 + lr)*LD;
#pragma unroll
      for (int cf = 0; cf < 4; cf++) {
        *(unsigned*)(pr + cf*16 + lg*4)     = cvt_pk_bf16(p[cf*4+0], p[cf*4+1]);
        *(unsigned*)(pr + cf*16 + lg*4 + 2) = cvt_pk_bf16(p[cf*4+2], p[cf*4+3]);
      }
    }
    short8 bp0 = *(const short8*)(Ps + (w*16 + lr)*LD + lg*8);
    short8 bp1 = *(const short8*)(Ps + (w*16 + lr)*LD + 32 + lg*8);
#pragma unroll
    for (int df = 0; df < 4; df++) {
      short8 av0 = *(const short8*)(Vsb + (df*16 + lr)*LD + lg*8);
      short8 av1 = *(const short8*)(Vsb + (df*16 + lr)*LD + 32 + lg*8);
      acc[df] = __builtin_amdgcn_mfma_f32_16x16x32_bf16(av0, bp0, acc[df], 0,0,0);
      acc[df] = __builtin_amdgcn_mfma_f32_16x16x32_bf16(av1, bp1, acc[df], 0,0,0);
    }
    if (kt < 63) {
      STOREKV((kt + 1) & 1);
      __syncthreads();     // one barrier/tile; dbuf keeps phases disjoint
    }
  }
#undef LOADKV
#undef STOREKV
  li += __shfl_xor(li, 16);
  li += __shfl_xor(li, 32);
  const float inv = 1.f / li;
  const long long row = (long long)b*4096 + q0 + w*16 + lr;
  unsigned short* ob = inb + row*256 + 192 + lg*4;
#pragma unroll
  for (int df = 0; df < 4; df++) {
    *(unsigned*)(ob + df*16)     = cvt_pk_bf16(acc[df][0]*inv, acc[df][1]*inv);
    *(unsigned*)(ob + df*16 + 2) = cvt_pk_bf16(acc[df][2]*inv, acc[df][3]*inv);
  }
}

// ====================== stage A: flash3 + all scores =======================
__global__ __launch_bounds__(256) void stageA_k(
    const unsigned short* __restrict__ Qu, const unsigned short* __restrict__ Ku,
    const unsigned short* __restrict__ Vu,
    float* __restrict__ Sp0, float* __restrict__ S1, float* __restrict__ S2,
    unsigned short* __restrict__ inb)
{
  const int bid = blockIdx.x;
  if (bid < 256) {                       // flash3 (longest) first
    flash3_body(Qu+3145728, Ku+3145728, Vu+3145728, inb, bid & 63, bid >> 6);
  } else if (bid < 264) {                // s0 scores: 8 blocks, wave tasks
    s0_scores_wave(Qu, Ku, Sp0, bid - 256);
  } else if (bid < 280) {                // s1 scores: grid (2,2,4)
    int q = bid - 264;
    gemm_nt_body<0>(Qu+1048576, Ku+1048576, (void*)S1, nullptr,
        256, 256, 1024, 1024, 1024, 256, 262144, 262144, 65536, 0.03125f,
        q & 1, (q >> 1) & 1, q >> 2);
  } else {                               // s2 scores: grid (8,8,4)
    int q = bid - 280;
    gemm_nt_body<0>(Qu+2097152, Ku+2097152, (void*)S2, nullptr,
        1024, 1024, 256, 256, 256, 1024, 262144, 262144, 1048576, 0.0625f,
        q & 7, (q >> 3) & 7, q >> 6);
  }
}

// ====================== stage B: all softmaxes =============================
// Vectorized: lane l owns CNT contiguous elements (float4 loads, packed
// bf16 stores). Full-row reduce via 64-lane shuffles. Layout of P unchanged.
template<int CNT>
__device__ void softmax_row(const float* __restrict__ S,
                            unsigned short* __restrict__ P, long long row)
{
  const int l = threadIdx.x & 63;
  const float* p = S + row*(CNT*64) + l*CNT;
  unsigned short* o = P + row*(CNT*64) + l*CNT;
  float v[CNT];
#pragma unroll
  for (int i = 0; i < CNT; i += 4) {
    float4 f = *(const float4*)(p + i);
    v[i] = f.x; v[i+1] = f.y; v[i+2] = f.z; v[i+3] = f.w;
  }
  float mx = v[0];
#pragma unroll
  for (int i = 1; i < CNT; i++) mx = fmaxf(mx, v[i]);
#pragma unroll
  for (int off = 1; off < 64; off <<= 1) mx = fmaxf(mx, __shfl_xor(mx, off, 64));
  float sum = 0.f;
#pragma unroll
  for (int i = 0; i < CNT; i++) { v[i] = __expf(v[i] - mx); sum += v[i]; }
#pragma unroll
  for (int off = 1; off < 64; off <<= 1) sum += __shfl_xor(sum, off, 64);
  const float inv = 1.f / sum;
#pragma unroll
  for (int i = 0; i < CNT; i += 4) {
    unsigned w0 = cvt_pk_bf16(v[i]*inv,   v[i+1]*inv);
    unsigned w1 = cvt_pk_bf16(v[i+2]*inv, v[i+3]*inv);
    *(uint2*)(o + i) = make_uint2(w0, w1);
  }
}

__global__ __launch_bounds__(256) void stageB_k(
    const float* __restrict__ Sp0, unsigned short* __restrict__ P0,
    const float* __restrict__ S1, unsigned short* __restrict__ P1,
    const float* __restrict__ S2, unsigned short* __restrict__ P2)
{
  const int bid = blockIdx.x, t = threadIdx.x, l = t & 63, w = t >> 6;
  if (bid < 1024) {                      // s2: 4096 rows, CNT=16
    softmax_row<16>(S2, P2, (long long)bid*4 + w);
  } else if (bid < 1280) {               // s1: 1024 rows, CNT=4
    softmax_row<4>(S1, P1, (long long)(bid - 1024)*4 + w);
  } else {                               // s0: reduce 8 partials + softmax
    const int row = (bid - 1280)*4 + w;  // < 256
    const int b = row >> 6, r = row & 63;
    float v = 0.f;
#pragma unroll
    for (int ks = 0; ks < 8; ks++)
      v += Sp0[(((long long)(ks*4 + b)*64 + r) << 6) + l];
    v *= 0.015625f;
    float mx = v;
#pragma unroll
    for (int off = 1; off < 64; off <<= 1) mx = fmaxf(mx, __shfl_xor(mx, off, 64));
    float e = __expf(v - mx), sum = e;
#pragma unroll
    for (int off = 1; off < 64; off <<= 1) sum += __shfl_xor(sum, off, 64);
    P0[(row << 6) + l] = f2bf(e / sum);
  }
}

// ====================== stage C: all PV GEMMs -> bf16 NHWC =================
__global__ __launch_bounds__(256) void stageC_k(
    const unsigned short* __restrict__ P0, const unsigned short* __restrict__ P1,
    const unsigned short* __restrict__ P2, const unsigned short* __restrict__ Vu,
    unsigned short* __restrict__ inb)
{
  const int bid = blockIdx.x;
  if (bid < 128) {                       // s0 PV: grid (32,1,4), scale 0
    int q = bid;
    gemm_nt_body<2,3>(P0, Vu, (void*)inb, nullptr,
        64, 4096, 64, 64, 64, 0, 4096, 262144, 0, 1.0f,
        q & 31, 0, q >> 5);
  } else if (bid < 192) {                // s1 PV: grid (8,2,4), scale 1
    int q = bid - 128;
    gemm_nt_body<2,2>(P1, Vu+1048576, (void*)inb, nullptr,
        256, 1024, 256, 256, 256, 0, 65536, 262144, 0, 1.0f,
        q & 7, (q >> 3) & 1, q >> 4);
  } else {                               // s2 PV: grid (2,8,4), scale 2
    int q = bid - 192;
    gemm_nt_body<2,1>(P2, Vu+2097152, (void*)inb, nullptr,
        1024, 256, 1024, 1024, 1024, 0, 1048576, 262144, 0, 1.0f,
        q & 1, (q >> 1) & 7, q >> 4);
  }
}

// ====================== 3x3 conv: dbuf + reg-stage + A-preload =============
// Writes z as bf16 (halves conv write + both BN read legs).
__global__ __launch_bounds__(512) void conv_mfma_k(
    const unsigned short* __restrict__ inb, const unsigned short* __restrict__ Wb,
    const float* __restrict__ bias, unsigned short* __restrict__ zb)
{
  __shared__ unsigned short lds[2][6*66*32];   // 2 x 25,344 B
  const int t = threadIdx.x;
  const int l = t & 63, wid = t >> 6;          // 8 waves
  const int lr = l & 15, lg = l >> 4;
  const int waveM = wid >> 2, waveN = wid & 3;
  const int b = blockIdx.x >> 4, y0 = (blockIdx.x & 15) * 4;
  const int oc0 = blockIdx.y * 64 + waveM * 32;
  const long long inbase = (long long)b * 1048576;
  const int kgrp = lg * 8;

  f32x4 acc[2][4] = {};
  uint4 sreg[4];

#define CLOAD(IC0) do { \
    _Pragma("unroll") \
    for (int i = 0; i < 4; i++) { \
      int q = t + i*512; \
      if (q < 1584) { \
        int ic8 = q & 3, cc = (q >> 2) % 66, rr = q / 264; \
        int gy = y0 - 1 + rr, gx = cc - 1; \
        uint4 v = make_uint4(0u,0u,0u,0u); \
        if ((unsigned)gy < 64u && (unsigned)gx < 64u) \
          v = *(const uint4*)(inb + inbase + ((long long)(gy*64+gx))*256 \
                              + (IC0) + ic8*8); \
        sreg[i] = v; \
      } \
    } } while (0)
#define CSTORE(BUF) do { \
    _Pragma("unroll") \
    for (int i = 0; i < 4; i++) { \
      int q = t + i*512; \
      if (q < 1584) *(uint4*)(&lds[BUF][q*8]) = sreg[i]; \
    } } while (0)

  CLOAD(0);
  CSTORE(0);
  __syncthreads();

  for (int c = 0; c < 8; ++c) {
    const int ic0 = c * 32;
    if (c < 7) CLOAD(ic0 + 32);
    const unsigned short* wbase = Wb + (long long)(oc0 + lr)*256 + ic0 + kgrp;
    short8 afr[9][2];
#pragma unroll
    for (int tap = 0; tap < 9; tap++) {
      afr[tap][0] = *(const short8*)(wbase + (long long)tap*65536);
      afr[tap][1] = *(const short8*)(wbase + (long long)tap*65536 + 16*256);
    }
    const unsigned short* L = lds[c & 1];
#pragma unroll
    for (int ky = 0; ky < 3; ky++) {
#pragma unroll
      for (int kx = 0; kx < 3; kx++) {
        const int tap = ky*3 + kx;
#pragma unroll
        for (int nf = 0; nf < 4; nf++) {
          int pix = waveN*64 + nf*16 + lr;
          int rp = pix >> 6, xx = pix & 63;
          short8 bf = *(const short8*)(L + ((rp + ky)*66 + xx + kx)*32 + kgrp);
          acc[0][nf] = __builtin_amdgcn_mfma_f32_16x16x32_bf16(
              afr[tap][0], bf, acc[0][nf], 0, 0, 0);
          acc[1][nf] = __builtin_amdgcn_mfma_f32_16x16x32_bf16(
              afr[tap][1], bf, acc[1][nf], 0, 0, 0);
        }
      }
    }
    if (c < 7) {
      CSTORE((c + 1) & 1);
      __syncthreads();
    }
  }
#undef CLOAD
#undef CSTORE

  const long long zbase = ((long long)b * 256) << 12;
#pragma unroll
  for (int mf = 0; mf < 2; mf++) {
#pragma unroll
    for (int r = 0; r < 4; r++) {
      const int oc = oc0 + mf*16 + lg*4 + r;
      const float bb = bias[oc];
      const long long rowbase = zbase + ((long long)oc << 12) + y0*64;
#pragma unroll
      for (int nf = 0; nf < 4; nf++) {
        int pix = waveN*64 + nf*16 + lr;
        zb[rowbase + pix] = f2bf(acc[mf][nf][r] + bb);
      }
    }
  }
}

// ====================== BatchNorm + LeakyReLU (bf16 z) =====================
__global__ __launch_bounds__(256) void bn_stats_k(
    const unsigned short* __restrict__ zb, float* __restrict__ stats)
{
  const int ch = blockIdx.x, t = threadIdx.x;
  float s = 0.f, q = 0.f;
  for (int b = 0; b < 4; b++) {
    const unsigned short* p = zb + ((long long)(b*256 + ch) << 12);
    for (int i = t; i < 512; i += 256) {    // 512 x 8 bf16 = 4096 elems
      short8 v8 = *(const short8*)(p + i*8);
#pragma unroll
      for (int j = 0; j < 8; j++) {
        float v = bf2f((unsigned short)v8[j]);
        s += v; q += v*v;
      }
    }
  }
  __shared__ float rs[256], rq[256];
  rs[t] = s; rq[t] = q; __syncthreads();
  for (int st = 128; st > 0; st >>= 1) {
    if (t < st) { rs[t] += rs[t+st]; rq[t] += rq[t+st]; }
    __syncthreads();
  }
  if (t == 0) {
    float mean = rs[0] * (1.f/16384.f);
    float var  = rq[0] * (1.f/16384.f) - mean*mean;
    stats[ch]       = mean;
    stats[256 + ch] = rsqrtf(var + 1e-5f);
  }
}

__global__ __launch_bounds__(256) void bn_apply_k(
    const unsigned short* __restrict__ zb, const float* __restrict__ stats,
    const float* __restrict__ gamma, const float* __restrict__ beta,
    float* __restrict__ out)
{
  long long i4 = ((long long)blockIdx.x*256 + threadIdx.x) * 4;
  int ch = (int)((i4 >> 12) & 255);
  float mean = stats[ch], rsg = stats[256 + ch];
  float g = gamma[ch], bt = beta[ch];
  ushort4 v = *(const ushort4*)(zb + i4);
  float r[4] = {bf2f(v.x), bf2f(v.y), bf2f(v.z), bf2f(v.w)};
#pragma unroll
  for (int j = 0; j < 4; j++) {
    float u = (r[j] - mean) * rsg * g + bt;
    r[j] = u > 0.f ? u : 0.2f * u;
  }
  *(float4*)(out + i4) = make_float4(r[0], r[1], r[2], r[3]);
}

// ---------------------------------------------------------------------------
extern "C" void kernel_launch(void* const* d_in, const int* in_sizes, int n_in,
                              void* d_out, int out_size, void* d_ws, size_t ws_size,
                              hipStream_t stream)
{
  const float* x     = (const float*)d_in[0];
  const float* wq    = (const float*)d_in[1];
  const float* bq    = (const float*)d_in[2];
  const float* wk    = (const float*)d_in[3];
  const float* bk    = (const float*)d_in[4];
  const float* wv    = (const float*)d_in[5];
  const float* bv    = (const float*)d_in[6];
  const float* w_out = (const float*)d_in[7];
  const float* b_out = (const float*)d_in[8];
  const float* gamma = (const float*)d_in[9];
  const float* beta  = (const float*)d_in[10];
  float* out = (float*)d_out;

  float* ws = (float*)d_ws;
  unsigned short* xb  = (unsigned short*)(ws + OFF_XB);
  unsigned short* Qu  = (unsigned short*)(ws + OFF_QB);
  unsigned short* Ku  = Qu + 4194304;
  unsigned short* Vu  = Qu + 8388608;
  float* S2  = ws + OFF_SS;
  unsigned short* P2 = (unsigned short*)(ws + OFF_PP);
  unsigned short* Wqk = (unsigned short*)(ws + OFF_WQK);
  float* biasQ = ws + OFF_BIA;
  unsigned short* Wcv = (unsigned short*)(ws + OFF_WCV);
  float* St  = ws + OFF_STT;
  float* Sp0 = ws + OFF_SP0;
  float* S1  = ws + OFF_S1;
  unsigned short* P0 = (unsigned short*)(ws + OFF_P0);
  unsigned short* P1 = (unsigned short*)(ws + OFF_P1);
  unsigned short* inb = (unsigned short*)(ws + OFF_XB);   // alias: xb dead
  unsigned short* zb  = (unsigned short*)(ws + OFF_YT);   // conv out bf16

  dim3 blk(256);

  // 1) prep: x transpose + all weight conversions
  prep_k<<<dim3(3328), blk, 0, stream>>>(
      x, xb, wq, wk, wv, bq, bk, bv, Wqk, biasQ, w_out, Wcv);

  // 2) fused QKV projection -> bf16 token layouts (V transposed)
  qkv_k<<<dim3(32,6,4), blk, 0, stream>>>(Wqk, xb, Qu, biasQ);

  // 3) stage A: flash3 (no-split, dbuf, direct NHWC) + all scores
  stageA_k<<<dim3(536), blk, 0, stream>>>(Qu, Ku, Vu, Sp0, S1, S2, inb);

  // 4) stage B: all softmaxes (vectorized)
  stageB_k<<<dim3(1344), blk, 0, stream>>>(Sp0, P0, S1, P1, S2, P2);

  // 5) stage C: all PV GEMMs -> bf16 NHWC (ch 0-191)
  stageC_k<<<dim3(256), blk, 0, stream>>>(P0, P1, P2, Vu, inb);

  // 6) 3x3 conv (dbuf, 8 waves) -> bf16 z
  conv_mfma_k<<<dim3(64,4), dim3(512), 0, stream>>>(inb, Wcv, b_out, zb);

  // 7) BN + LeakyReLU (bf16 z)
  bn_stats_k<<<dim3(256), blk, 0, stream>>>(zb, St);
  bn_apply_k<<<dim3(4096), blk, 0, stream>>>(zb, St, gamma, beta, out);
}